// Round 6
// baseline (445.127 us; speedup 1.0000x reference)
//
#include <hip/hip_runtime.h>

// Conv2D_80796924772741: grouped (per-F) 3x3x1 valid correlation + int8 requantize.
// Harness protocol: int8 tensors are widened to int32 on both input AND output.
//   x: int32 [64,514,514,4], w: int32 [64,3,3,1], b: int32 [64]
//   out: int32 [64,512,512,4]  (quantized int8 values stored as int32)
// Quant: reduced_mantissa = (1305500416 + (1<<15)) >> 16 = 19920
//        total_shifts = 15 - (-7) = 22, out_zp = -5, clip [-128,127]
// Identity used: ((acc*19920 + 2^21) >> 22) == ((acc*4980 + 2^19) >> 20) exactly
// (divide numerator and denominator by 4; 19920 = 4*4980). |acc| <= 9*128*128+1000
// = 148456, so acc*4980 <= 7.4e8 < 2^31 — pure 32-bit requantize, no i64 mul.
//
// NOTE: __builtin_nontemporal_store requires a clang ext_vector type —
// HIP's int4 (HIP_vector_type class) is rejected. v4i below is layout- and
// alignment-identical (16 B) and works for both plain loads and NT stores.

typedef int v4i __attribute__((ext_vector_type(4)));

#define NF 64
#define HH 514
#define WW 514
#define OH 512
#define OW 512
#define RB 8                        // output rows per thread (halo amp = (RB+2)/RB)
#define NWG (2 * (OH / RB) * NF)    // 2 * 64 * 64 = 8192 workgroups

__device__ __forceinline__ int quantize(int acc) {
    int r = ((acc * 4980 + (1 << 19)) >> 20) - 5;   // arithmetic shift + OUT_ZP
    return max(-128, min(127, r));
}

__global__ __launch_bounds__(256) void conv2d_q_kernel(const int* __restrict__ x,
                                                       const int* __restrict__ w,
                                                       const int* __restrict__ b,
                                                       int* __restrict__ out) {
    // Bijective XCD-chunked swizzle (NWG % 8 == 0): hardware round-robins
    // consecutive dispatch ids across the 8 XCDs; remap so each XCD owns a
    // contiguous chunk -> vertically-adjacent tiles (which share 2 halo rows)
    // land on the same XCD's L2 instead of always re-fetching from HBM.
    const int wg  = blockIdx.x;
    const int swz = (wg & 7) * (NWG / 8) + (wg >> 3);
    const int f   = swz >> 7;                 // 128 wgs per filter slice (2 x 64)
    const int rem = swz & 127;
    const int oh0 = (rem >> 1) * RB;
    const int ow  = (rem & 1) * 256 + threadIdx.x;   // v4i-granular column

    // Wave-uniform weights + bias -> scalar loads.
    int wgt[9];
#pragma unroll
    for (int k = 0; k < 9; ++k) wgt[k] = w[f * 9 + k];
    const int bias = b[f];

    const v4i* __restrict__ xv = reinterpret_cast<const v4i*>(x);
    v4i* __restrict__ ov = reinterpret_cast<v4i*>(out);

    int acc[RB][4];
#pragma unroll
    for (int r = 0; r < RB; ++r)
#pragma unroll
        for (int c = 0; c < 4; ++c) acc[r][c] = bias;

    const int xbase = (f * HH + oh0) * WW + ow;   // v4i-granular index

    // Stream RB+2 input rows; row h feeds output rows r = h-2..h (weight row m = h-r).
#pragma unroll
    for (int h = 0; h < RB + 2; ++h) {
        const v4i t0 = xv[xbase + h * WW + 0];
        const v4i t1 = xv[xbase + h * WW + 1];
        const v4i t2 = xv[xbase + h * WW + 2];
#pragma unroll
        for (int r = 0; r < RB; ++r) {
            const int m = h - r;
            if (m >= 0 && m < 3) {
                const int c0 = wgt[m * 3 + 0];
                const int c1 = wgt[m * 3 + 1];
                const int c2 = wgt[m * 3 + 2];
#pragma unroll
                for (int c = 0; c < 4; ++c)
                    acc[r][c] += t0[c] * c0 + t1[c] * c1 + t2[c] * c2;
            }
        }
    }

    // Output is never re-read: non-temporal stores keep L2 free for input halo.
    const int obase = (f * OH + oh0) * OW + ow;
#pragma unroll
    for (int r = 0; r < RB; ++r) {
        v4i o;
#pragma unroll
        for (int c = 0; c < 4; ++c) o[c] = quantize(acc[r][c]);
        __builtin_nontemporal_store(o, &ov[obase + r * OW]);
    }
}

extern "C" void kernel_launch(void* const* d_in, const int* in_sizes, int n_in,
                              void* d_out, int out_size, void* d_ws, size_t ws_size,
                              hipStream_t stream) {
    const int* x = (const int*)d_in[0];
    const int* w = (const int*)d_in[1];
    const int* b = (const int*)d_in[2];
    int* out = (int*)d_out;

    dim3 grid(NWG, 1, 1);   // 8192 blocks, XCD-swizzled in-kernel
    dim3 block(256, 1, 1);
    conv2d_q_kernel<<<grid, block, 0, stream>>>(x, w, b, out);
}

// Round 7
// 437.311 us; speedup vs baseline: 1.0179x; 1.0179x over previous
//
#include <hip/hip_runtime.h>

// Conv2D_80796924772741: grouped (per-F) 3x3x1 valid correlation + int8 requantize.
// Harness protocol: int8 tensors are widened to int32 on both input AND output.
//   x: int32 [64,514,514,4], w: int32 [64,3,3,1], b: int32 [64]
//   out: int32 [64,512,512,4]  (quantized int8 values stored as int32)
// Quant: reduced_mantissa = (1305500416 + (1<<15)) >> 16 = 19920
//        total_shifts = 15 - (-7) = 22, out_zp = -5, clip [-128,127]
// Identity used: ((acc*19920 + 2^21) >> 22) == ((acc*4980 + 2^19) >> 20) exactly
// (divide numerator and denominator by 4; 19920 = 4*4980). |acc| <= 9*128*128+1000
// = 148456, so acc*4980 <= 7.4e8 < 2^31 — pure 32-bit requantize, no i64 mul.
//
// R6 post-mortem: NT stores REGRESSED (conv ~100 -> ~114 us vs RB=4 baseline).
// Theory: nt bypasses L2 write-aggregation; plain stores drain through L2 at
// ~6.5 TB/s (the harness fills prove it). Reverted to plain dwordx4 stores.
// v4i (clang ext_vector) kept — layout-identical to int4, same codegen.

typedef int v4i __attribute__((ext_vector_type(4)));

#define NF 64
#define HH 514
#define WW 514
#define OH 512
#define OW 512
#define RB 8                        // output rows per thread (halo amp = (RB+2)/RB)
#define NWG (2 * (OH / RB) * NF)    // 2 * 64 * 64 = 8192 workgroups

__device__ __forceinline__ int quantize(int acc) {
    int r = ((acc * 4980 + (1 << 19)) >> 20) - 5;   // arithmetic shift + OUT_ZP
    return max(-128, min(127, r));
}

__global__ __launch_bounds__(256) void conv2d_q_kernel(const int* __restrict__ x,
                                                       const int* __restrict__ w,
                                                       const int* __restrict__ b,
                                                       int* __restrict__ out) {
    // Bijective XCD-chunked swizzle (NWG % 8 == 0): hardware round-robins
    // consecutive dispatch ids across the 8 XCDs; remap so each XCD owns a
    // contiguous chunk -> vertically-adjacent tiles (which share 2 halo rows)
    // land on the same XCD's L2 instead of always re-fetching from HBM.
    const int wg  = blockIdx.x;
    const int swz = (wg & 7) * (NWG / 8) + (wg >> 3);
    const int f   = swz >> 7;                 // 128 wgs per filter slice (2 x 64)
    const int rem = swz & 127;
    const int oh0 = (rem >> 1) * RB;
    const int ow  = (rem & 1) * 256 + threadIdx.x;   // v4i-granular column

    // Wave-uniform weights + bias -> scalar loads.
    int wgt[9];
#pragma unroll
    for (int k = 0; k < 9; ++k) wgt[k] = w[f * 9 + k];
    const int bias = b[f];

    const v4i* __restrict__ xv = reinterpret_cast<const v4i*>(x);
    v4i* __restrict__ ov = reinterpret_cast<v4i*>(out);

    int acc[RB][4];
#pragma unroll
    for (int r = 0; r < RB; ++r)
#pragma unroll
        for (int c = 0; c < 4; ++c) acc[r][c] = bias;

    const int xbase = (f * HH + oh0) * WW + ow;   // v4i-granular index

    // Stream RB+2 input rows; row h feeds output rows r = h-2..h (weight row m = h-r).
#pragma unroll
    for (int h = 0; h < RB + 2; ++h) {
        const v4i t0 = xv[xbase + h * WW + 0];
        const v4i t1 = xv[xbase + h * WW + 1];
        const v4i t2 = xv[xbase + h * WW + 2];
#pragma unroll
        for (int r = 0; r < RB; ++r) {
            const int m = h - r;
            if (m >= 0 && m < 3) {
                const int c0 = wgt[m * 3 + 0];
                const int c1 = wgt[m * 3 + 1];
                const int c2 = wgt[m * 3 + 2];
#pragma unroll
                for (int c = 0; c < 4; ++c)
                    acc[r][c] += t0[c] * c0 + t1[c] * c1 + t2[c] * c2;
            }
        }
    }

    // Plain stores: output drains through L2 (write-aggregated) to HBM.
    const int obase = (f * OH + oh0) * OW + ow;
#pragma unroll
    for (int r = 0; r < RB; ++r) {
        v4i o;
#pragma unroll
        for (int c = 0; c < 4; ++c) o[c] = quantize(acc[r][c]);
        ov[obase + r * OW] = o;
    }
}

extern "C" void kernel_launch(void* const* d_in, const int* in_sizes, int n_in,
                              void* d_out, int out_size, void* d_ws, size_t ws_size,
                              hipStream_t stream) {
    const int* x = (const int*)d_in[0];
    const int* w = (const int*)d_in[1];
    const int* b = (const int*)d_in[2];
    int* out = (int*)d_out;

    dim3 grid(NWG, 1, 1);   // 8192 blocks, XCD-swizzled in-kernel
    dim3 block(256, 1, 1);
    conv2d_q_kernel<<<grid, block, 0, stream>>>(x, w, b, out);
}